// Round 1
// baseline (1960.780 us; speedup 1.0000x reference)
//
#include <hip/hip_runtime.h>
#include <hip/hip_bf16.h>
#include <stdint.h>

#define TOKENS 8192
#define OUT_F  16384
#define IN_F   4096

typedef short bf16x8 __attribute__((ext_vector_type(8)));
typedef float f32x4  __attribute__((ext_vector_type(4)));

__device__ __forceinline__ unsigned short bf16_rne(float f) {
    union { float f; unsigned int u; } v; v.f = f;
    unsigned int u = v.u;
    u += 0x7fffu + ((u >> 16) & 1u);   // round-to-nearest-even (inputs are finite normals, no NaN path)
    return (unsigned short)(u >> 16);
}

__device__ __forceinline__ unsigned int pack_bf16x2(float a, float b) {
    return (unsigned int)bf16_rne(a) | ((unsigned int)bf16_rne(b) << 16);
}

// async global->LDS DMA, 16B/lane. LDS dst is wave-uniform base + lane*16.
__device__ __forceinline__ void async_cp16(const void* gptr, void* ldsptr) {
    __builtin_amdgcn_global_load_lds(
        (const __attribute__((address_space(1))) unsigned int*)gptr,
        (__attribute__((address_space(3))) unsigned int*)ldsptr,
        16, 0, 0);
}

// ---------------- pre-pass 1: x fp32 -> bf16 ----------------
__global__ __launch_bounds__(256) void cvt_input_kernel(
    const float* __restrict__ in, unsigned short* __restrict__ out, int n8)
{
    int i = blockIdx.x * 256 + threadIdx.x;
    if (i >= n8) return;
    size_t base = (size_t)i * 8;
    float4 a = *(const float4*)(in + base);
    float4 b = *(const float4*)(in + base + 4);
    uint4 p;
    p.x = pack_bf16x2(a.x, a.y);  p.y = pack_bf16x2(a.z, a.w);
    p.z = pack_bf16x2(b.x, b.y);  p.w = pack_bf16x2(b.z, b.w);
    *(uint4*)(out + base) = p;
}

// ---------------- pre-pass 2: idx -> bf16(LUT[idx]) ----------------
__global__ __launch_bounds__(256) void dequant_kernel(
    const int* __restrict__ idx, const float* __restrict__ lut,
    unsigned short* __restrict__ out, int n8)
{
    __shared__ float slut[256];
    slut[threadIdx.x] = lut[threadIdx.x];
    __syncthreads();
    int i = blockIdx.x * 256 + threadIdx.x;
    if (i >= n8) return;
    size_t base = (size_t)i * 8;
    int4 i0 = *(const int4*)(idx + base);
    int4 i1 = *(const int4*)(idx + base + 4);
    uint4 p;
    p.x = pack_bf16x2(slut[i0.x], slut[i0.y]);
    p.y = pack_bf16x2(slut[i0.z], slut[i0.w]);
    p.z = pack_bf16x2(slut[i1.x], slut[i1.y]);
    p.w = pack_bf16x2(slut[i1.z], slut[i1.w]);
    *(uint4*)(out + base) = p;
}

// ---------------- GEMM: C[M,N] = A[M,K] * B[N,K]^T + bias ----------------
// MODE 0: A,B are pre-converted bf16 in ws, staged via global_load_lds (m97 structure)
// MODE 1: fused fallback — A fp32 + idx dequant converted in-register during staging
template<int MODE>
__global__ __launch_bounds__(256) void palett_gemm(
    const unsigned short* __restrict__ A,     // [M][K] bf16 (MODE 0)
    const unsigned short* __restrict__ B,     // [N][K] bf16 (MODE 0)
    const float* __restrict__ Af,             // [M][K] fp32 (MODE 1)
    const int* __restrict__ Widx,             // [N][K] int32 (MODE 1)
    const float* __restrict__ lut,
    const float* __restrict__ bias,
    float* __restrict__ out)
{
    __shared__ __align__(16) unsigned short smA[128 * 32];  // 8 KB
    __shared__ __align__(16) unsigned short smB[128 * 32];  // 8 KB
    __shared__ float slut[256];

    const int t    = threadIdx.x;
    const int w    = t >> 6;       // wave 0..3
    const int l    = t & 63;
    const int quad = l >> 4;
    const int r16  = l & 15;
    const int wr   = w >> 1;       // wave row (2x2 wave grid, 64x64 per wave)
    const int wc   = w & 1;

    const int m0 = blockIdx.y * 128;
    const int n0 = blockIdx.x * 128;

    // staging geometry: 256 threads x 8 bf16 = 64 rows x 32 cols per round
    const int g0  = t * 8;
    const int row = g0 >> 5;       // 0..63
    const int col = g0 & 31;       // multiple of 8

    char* const smA_c = (char*)smA;
    char* const smB_c = (char*)smB;

    if constexpr (MODE == 1) {
        slut[t] = lut[t];
        __syncthreads();
    }

    // LDS fragment read offsets (bytes): A[m=lane&15][k=quad*8+j], tile row-major [128][32] bf16
    uint32_t aoff[4], boff[4];
#pragma unroll
    for (int i = 0; i < 4; ++i) {
        aoff[i] = (uint32_t)(((wr * 64 + i * 16 + r16) * 32 + quad * 8) * 2);
        boff[i] = (uint32_t)(((wc * 64 + i * 16 + r16) * 32 + quad * 8) * 2);
    }

    f32x4 acc[4][4] = {};

    const unsigned short* a0 = nullptr; const unsigned short* a1 = nullptr;
    const unsigned short* b0 = nullptr; const unsigned short* b1 = nullptr;
    const float* af0 = nullptr; const float* af1 = nullptr;
    const int* wi0 = nullptr;   const int* wi1 = nullptr;
    if constexpr (MODE == 0) {
        a0 = A + (size_t)(m0 + row) * IN_F + col;
        a1 = A + (size_t)(m0 + row + 64) * IN_F + col;
        b0 = B + (size_t)(n0 + row) * IN_F + col;
        b1 = B + (size_t)(n0 + row + 64) * IN_F + col;
    } else {
        af0 = Af + (size_t)(m0 + row) * IN_F + col;
        af1 = Af + (size_t)(m0 + row + 64) * IN_F + col;
        wi0 = Widx + (size_t)(n0 + row) * IN_F + col;
        wi1 = Widx + (size_t)(n0 + row + 64) * IN_F + col;
    }

    // wave-uniform LDS staging bases: byte off = round*4096 + w*1024 (+ lane*16 by HW)
    const uint32_t ldsw0 = (uint32_t)(w * 1024);
    const uint32_t ldsw1 = (uint32_t)(4096 + w * 1024);

    for (int k0 = 0; k0 < IN_F; k0 += 32) {
        if constexpr (MODE == 0) {
            async_cp16(a0 + k0, smA_c + ldsw0);
            async_cp16(a1 + k0, smA_c + ldsw1);
            async_cp16(b0 + k0, smB_c + ldsw0);
            async_cp16(b1 + k0, smB_c + ldsw1);
        } else {
            float4 x0 = *(const float4*)(af0 + k0);
            float4 x1 = *(const float4*)(af0 + k0 + 4);
            uint4 p;
            p.x = pack_bf16x2(x0.x, x0.y); p.y = pack_bf16x2(x0.z, x0.w);
            p.z = pack_bf16x2(x1.x, x1.y); p.w = pack_bf16x2(x1.z, x1.w);
            *(uint4*)(smA_c + t * 16) = p;
            x0 = *(const float4*)(af1 + k0);
            x1 = *(const float4*)(af1 + k0 + 4);
            p.x = pack_bf16x2(x0.x, x0.y); p.y = pack_bf16x2(x0.z, x0.w);
            p.z = pack_bf16x2(x1.x, x1.y); p.w = pack_bf16x2(x1.z, x1.w);
            *(uint4*)(smA_c + 4096 + t * 16) = p;

            int4 j0 = *(const int4*)(wi0 + k0);
            int4 j1 = *(const int4*)(wi0 + k0 + 4);
            p.x = pack_bf16x2(slut[j0.x], slut[j0.y]);
            p.y = pack_bf16x2(slut[j0.z], slut[j0.w]);
            p.z = pack_bf16x2(slut[j1.x], slut[j1.y]);
            p.w = pack_bf16x2(slut[j1.z], slut[j1.w]);
            *(uint4*)(smB_c + t * 16) = p;
            j0 = *(const int4*)(wi1 + k0);
            j1 = *(const int4*)(wi1 + k0 + 4);
            p.x = pack_bf16x2(slut[j0.x], slut[j0.y]);
            p.y = pack_bf16x2(slut[j0.z], slut[j0.w]);
            p.z = pack_bf16x2(slut[j1.x], slut[j1.y]);
            p.w = pack_bf16x2(slut[j1.z], slut[j1.w]);
            *(uint4*)(smB_c + 4096 + t * 16) = p;
        }
        __syncthreads();   // drains vmcnt (global_load_lds) / lgkm before use

        bf16x8 afr[4], bfr[4];
#pragma unroll
        for (int i = 0; i < 4; ++i) afr[i] = *(const bf16x8*)(smA_c + aoff[i]);
#pragma unroll
        for (int j = 0; j < 4; ++j) bfr[j] = *(const bf16x8*)(smB_c + boff[j]);
#pragma unroll
        for (int i = 0; i < 4; ++i)
#pragma unroll
            for (int j = 0; j < 4; ++j)
                acc[i][j] = __builtin_amdgcn_mfma_f32_16x16x32_bf16(
                    afr[i], bfr[j], acc[i][j], 0, 0, 0);
        __syncthreads();   // before next iteration overwrites LDS
    }

    // epilogue: C/D layout row=quad*4+reg (m), col=lane&15 (n); add bias, fp32 store
    float bj[4];
#pragma unroll
    for (int j = 0; j < 4; ++j) bj[j] = bias[n0 + wc * 64 + j * 16 + r16];

#pragma unroll
    for (int i = 0; i < 4; ++i) {
        const int mbase = m0 + wr * 64 + i * 16 + quad * 4;
#pragma unroll
        for (int j = 0; j < 4; ++j) {
            const int n = n0 + wc * 64 + j * 16 + r16;
#pragma unroll
            for (int v = 0; v < 4; ++v) {
                out[(size_t)(mbase + v) * OUT_F + n] = acc[i][j][v] + bj[j];
            }
        }
    }
}

extern "C" void kernel_launch(void* const* d_in, const int* in_sizes, int n_in,
                              void* d_out, int out_size, void* d_ws, size_t ws_size,
                              hipStream_t stream) {
    const float* input = (const float*)d_in[0];   // [8192][4096] fp32
    const int*   widx  = (const int*)d_in[1];     // [16384][4096] int32
    const float* lut   = (const float*)d_in[2];   // [256] fp32
    const float* bias  = (const float*)d_in[3];   // [16384] fp32
    float* out = (float*)d_out;                   // [8192][16384] fp32

    const size_t aBytes = (size_t)TOKENS * IN_F * sizeof(unsigned short); //  64 MB
    const size_t bBytes = (size_t)OUT_F  * IN_F * sizeof(unsigned short); // 128 MB

    dim3 grid(OUT_F / 128, TOKENS / 128);  // (128, 64) = 8192 blocks

    if (ws_size >= aBytes + bBytes) {
        unsigned short* wsA = (unsigned short*)d_ws;
        unsigned short* wsB = (unsigned short*)((char*)d_ws + aBytes);
        const int nA8 = (TOKENS * IN_F) / 8;   // 4194304
        const int nB8 = (OUT_F  * IN_F) / 8;   // 8388608
        cvt_input_kernel<<<(nA8 + 255) / 256, 256, 0, stream>>>(input, wsA, nA8);
        dequant_kernel<<<(nB8 + 255) / 256, 256, 0, stream>>>(widx, lut, wsB, nB8);
        palett_gemm<0><<<grid, 256, 0, stream>>>(wsA, wsB, nullptr, nullptr, lut, bias, out);
    } else {
        palett_gemm<1><<<grid, 256, 0, stream>>>(nullptr, nullptr, input, widx, lut, bias, out);
    }
}